// Round 14
// baseline (181.845 us; speedup 1.0000x reference)
//
#include <hip/hip_runtime.h>
#include <stdint.h>

typedef unsigned int u32;
typedef unsigned short u16;

#define N_  1024
#define F_  512
#define ALPHA 0.2f
#define TSTR2 72   // k_prep LDS tile stride (u16): 144 B rows -> 16B-aligned b128 reads, 2-way (free)

typedef __attribute__((ext_vector_type(8))) short short8;
typedef __attribute__((ext_vector_type(4))) float float4v;

union Frag { short8 s; u32 u[4]; };

static __device__ __forceinline__ float bits2f(u32 b){ union{u32 u; float f;} c; c.u=b; return c.f; }
static __device__ __forceinline__ u32   f2bits(float f){ union{float f_; u32 u;} c; c.f_=f; return c.u; }
static __device__ __forceinline__ float bflo(u32 p){ return bits2f(p<<16); }
static __device__ __forceinline__ float bfhi(u32 p){ return bits2f(p & 0xffff0000u); }
static __device__ __forceinline__ u32   f2bf(float f){ u32 u=f2bits(f); return (u + 0x7fffu + ((u>>16)&1u))>>16; }
static __device__ __forceinline__ u32   cvt_pk_bf16(float lo, float hi){
    u32 r; asm("v_cvt_pk_bf16_f32 %0, %1, %2" : "=v"(r) : "v"(lo), "v"(hi)); return r;
}
static __device__ __forceinline__ short8 u2s8(uint4 u){ Frag f; f.u[0]=u.x; f.u[1]=u.y; f.u[2]=u.z; f.u[3]=u.w; return f.s; }

// ---- kernel 1: w1 = W^T a1, w2 = W^T a2 (atomic partial sums into ws[0..1024)) ----
__global__ void k_w12(const float* __restrict__ W, const float* __restrict__ a1,
                      const float* __restrict__ a2, float* __restrict__ ws){
    int t = threadIdx.x;          // 256 threads: f = t and t+256
    int bo = blockIdx.x;          // 64 blocks: o-chunk of 8
    float s1a=0.f,s2a=0.f,s1b=0.f,s2b=0.f;
    #pragma unroll
    for(int i=0;i<8;i++){
        int o = bo*8+i;
        float av1 = a1[o], av2 = a2[o];
        float wa = W[o*F_ + t], wb = W[o*F_ + t + 256];
        s1a += wa*av1; s2a += wa*av2; s1b += wb*av1; s2b += wb*av2;
    }
    atomicAdd(&ws[t],       s1a); atomicAdd(&ws[512+t],     s2a);
    atomicAdd(&ws[t+256],   s1b); atomicAdd(&ws[512+t+256], s2b);
}

// ---- kernel 2: transpose X->XT bf16 + d1/d2 dots (R9 known-good, no atomics) ----
__global__ __launch_bounds__(1024)
void k_prep(const float* __restrict__ X, const float* __restrict__ ws,
            u16* __restrict__ XT, float* __restrict__ d1acc, float* __restrict__ d2acc){
    __shared__ u16 tile[4][64][TSTR2];   // 36 KB: [slice-group][f 64][m 64 +pad]
    __shared__ float dpart[2][4][64];    // 2 KB group-partial row dots

    const int t   = threadIdx.x;
    const int id  = blockIdx.x + (blockIdx.y << 4);   // 0..255
    const int xcd = id & 7, slot = id >> 3;
    const int b   = (xcd << 1) | (slot >> 4);
    const int m0  = (slot & 15) << 6;

    const int g    = t >> 8;             // slice group 0..3
    const int tid2 = t & 255;
    const int mg   = tid2 >> 4;          // 0..15
    const int m4   = mg * 4;
    const int fq   = (tid2 & 15) * 4;

    float4 v[2][4];
    #pragma unroll
    for(int p=0;p<2;p++){
        const float* Xb = X + ((size_t)(b*N_ + m0 + m4))*F_ + (p*4+g)*64 + fq;
        #pragma unroll
        for(int i=0;i<4;i++) v[p][i] = *(const float4*)(Xb + (size_t)i*F_);
    }

    float d1p[4]={0.f,0.f,0.f,0.f}, d2p[4]={0.f,0.f,0.f,0.f};
    #pragma unroll
    for(int p=0;p<2;p++){
        float4 w1q = *(const float4*)(ws + (p*4+g)*64 + fq);
        float4 w2q = *(const float4*)(ws + 512 + (p*4+g)*64 + fq);
        #pragma unroll
        for(int i=0;i<4;i++){
            d1p[i] += v[p][i].x*w1q.x + v[p][i].y*w1q.y + v[p][i].z*w1q.z + v[p][i].w*w1q.w;
            d2p[i] += v[p][i].x*w2q.x + v[p][i].y*w2q.y + v[p][i].z*w2q.z + v[p][i].w*w2q.w;
        }
    }

    #define TPOSE(P) { \
        u32 l0 = cvt_pk_bf16(v[P][0].x, v[P][1].x), h0 = cvt_pk_bf16(v[P][2].x, v[P][3].x); \
        *(uint2*)&tile[g][fq+0][m4] = (uint2){l0,h0}; \
        u32 l1 = cvt_pk_bf16(v[P][0].y, v[P][1].y), h1 = cvt_pk_bf16(v[P][2].y, v[P][3].y); \
        *(uint2*)&tile[g][fq+1][m4] = (uint2){l1,h1}; \
        u32 l2 = cvt_pk_bf16(v[P][0].z, v[P][1].z), h2 = cvt_pk_bf16(v[P][2].z, v[P][3].z); \
        *(uint2*)&tile[g][fq+2][m4] = (uint2){l2,h2}; \
        u32 l3 = cvt_pk_bf16(v[P][0].w, v[P][1].w), h3 = cvt_pk_bf16(v[P][2].w, v[P][3].w); \
        *(uint2*)&tile[g][fq+3][m4] = (uint2){l3,h3}; \
    }
    const int f_loc = tid2 >> 2;
    const int mo    = (tid2 & 3) * 16;
    #define XTOUT(P) { \
        uint4 q0 = *(const uint4*)&tile[g][f_loc][mo]; \
        uint4 q1 = *(const uint4*)&tile[g][f_loc][mo+8]; \
        u16* dst = XT + ((size_t)(b*F_ + (P*4+g)*64 + f_loc))*N_ + m0 + mo; \
        *(uint4*)dst = q0; *(uint4*)(dst+8) = q1; \
    }

    TPOSE(0)
    __syncthreads();
    XTOUT(0)
    __syncthreads();
    TPOSE(1)
    #pragma unroll
    for(int s2=1;s2<16;s2<<=1){
        #pragma unroll
        for(int i=0;i<4;i++){ d1p[i] += __shfl_xor(d1p[i],s2,64); d2p[i] += __shfl_xor(d2p[i],s2,64); }
    }
    if((t & 15) == 0){
        #pragma unroll
        for(int i=0;i<4;i++){ dpart[0][g][m4+i] = d1p[i]; dpart[1][g][m4+i] = d2p[i]; }
    }
    __syncthreads();
    XTOUT(1)
    if(t < 64){
        float s1 = dpart[0][0][t] + dpart[0][1][t] + dpart[0][2][t] + dpart[0][3][t];
        float s2 = dpart[1][0][t] + dpart[1][1][t] + dpart[1][2][t] + dpart[1][3][t];
        d1acc[b*N_ + m0 + t] = s1;
        d2acc[b*N_ + m0 + t] = s2;
    }
}

// ---- kernel 3: quartered producer/consumer pipeline over materialized P ----
// grid (16,16) = 256 blocks = 1/CU, 1024 threads = 16 waves. LDS 132 KB.
// R11's 2-barrier design with phase1/phase2 OVERLAP: 32 chunks split into 4 quarters.
// Segment q: { produce Q(q+1) (adj regs loaded last segment) | issue adj loads Q(q+2)
//              | consume Q(q) } -- no barrier inside a segment, so the adj HBM stream +
// produce VALU co-issue with MFMA/LDS/L2. Between segments only
// "s_waitcnt lgkmcnt(0); s_barrier" (pbuf publish; adj reg loads stay in flight).
// NOTE: no min-waves launch_bounds arg -- 132 KB LDS already forces 1 block/CU
// (= 4 waves/SIMD); leaving the VGPR cap to the allocator avoids forced spills.
__global__ __launch_bounds__(1024)
void k_main(const u16* __restrict__ XT, const int* __restrict__ adj,
            const float* __restrict__ d1acc, const float* __restrict__ d2acc,
            float* __restrict__ out){
    __shared__ u16 pbuf[32][4][512];   // 128 KB: P A-frags [chunk][nsub][lane*8]
    __shared__ u32 lds_e2[N_];         // 4 KB exp(f2)/exp(.2 f2) bf16-pair table
    __shared__ float dsums[64];        // row softmax denominators

    const int t    = threadIdx.x;
    const int lane = t & 63;
    const int wv   = t >> 6;           // 0..15
    const int fqq  = wv;               // consumer: f-slice of 32 (0..15)
    const int id   = blockIdx.x + (blockIdx.y << 4);
    const int xcd  = id & 7, slot = id >> 3;
    const int b    = (xcd << 1) | (slot >> 4);
    const int n0   = (slot & 15) << 6;
    const int r16  = lane & 15;
    const int quad = lane >> 4;
    const int rowL = lane >> 4;        // producer: row 0..3 within wave's quartet
    const int qL   = lane & 15;        // producer: col-pair index

    {
        float dv = d2acc[(size_t)b*N_ + t];
        lds_e2[t] = f2bf(__expf(dv)) | (f2bf(__expf(ALPHA*dv))<<16);
    }
    const float d1v  = d1acc[b*N_ + n0 + wv*4 + rowL];
    const float e1pL = __expf(d1v);
    const float e1nL = __expf(ALPHA*d1v);
    const int* adjLane = adj + ((size_t)(b*N_ + n0 + wv*4 + rowL))*N_ + qL*2;
    const u16* XTb = XT + (size_t)b*F_*N_;

    float dsum = 0.f;
    const int pOff = ((wv&3)*4 + rowL + (qL>>2)*16)*8 + (qL&3)*2;

    int2 adjR[8];                      // adj regs for one quarter (8 chunks)
    auto loadAdjQ = [&](int q){
        #pragma unroll
        for(int k=0;k<8;k++) adjR[k] = *(const int2*)(adjLane + (q*8+k)*32);
    };
    auto produceQ = [&](int q){
        #pragma unroll
        for(int k=0;k<8;k++){
            int c = q*8 + k;
            uint2 ev = *(const uint2*)(&lds_e2[c*32 + qL*2]);
            float p0 = fmaxf(e1pL*bflo(ev.x), e1nL*bfhi(ev.x)); p0 = adjR[k].x ? p0 : 0.f;
            float p1 = fmaxf(e1pL*bflo(ev.y), e1nL*bfhi(ev.y)); p1 = adjR[k].y ? p1 : 0.f;
            dsum += p0 + p1;
            *(u32*)(&pbuf[c][wv>>2][pOff]) = cvt_pk_bf16(p0, p1);
        }
    };

    // consumer state
    float4v acc[4][2];
    #pragma unroll
    for(int ns=0;ns<4;ns++){ acc[ns][0]=(float4v){0,0,0,0}; acc[ns][1]=(float4v){0,0,0,0}; }
    const u16* pA  = &pbuf[0][0][0];
    const u16* bB0 = XTb + (size_t)(fqq*32 +      r16)*N_ + quad*8;   // ct=0 rows
    const u16* bB1 = XTb + (size_t)(fqq*32 + 16 + r16)*N_ + quad*8;   // ct=1 rows

    #define LDCH(Aa,Ab,Ac,Ad,Bx,By,I) \
        Aa = *(const uint4*)(pA + ((I)*4+0)*512 + lane*8); \
        Ab = *(const uint4*)(pA + ((I)*4+1)*512 + lane*8); \
        Ac = *(const uint4*)(pA + ((I)*4+2)*512 + lane*8); \
        Ad = *(const uint4*)(pA + ((I)*4+3)*512 + lane*8); \
        Bx = *(const uint4*)(bB0 + (I)*32); \
        By = *(const uint4*)(bB1 + (I)*32);

    #define STEP(Aa,Ab,Ac,Ad,Bx,By) { \
        short8 sb0 = u2s8(Bx), sb1 = u2s8(By); \
        acc[0][0] = __builtin_amdgcn_mfma_f32_16x16x32_bf16(u2s8(Aa), sb0, acc[0][0],0,0,0); \
        acc[0][1] = __builtin_amdgcn_mfma_f32_16x16x32_bf16(u2s8(Aa), sb1, acc[0][1],0,0,0); \
        acc[1][0] = __builtin_amdgcn_mfma_f32_16x16x32_bf16(u2s8(Ab), sb0, acc[1][0],0,0,0); \
        acc[1][1] = __builtin_amdgcn_mfma_f32_16x16x32_bf16(u2s8(Ab), sb1, acc[1][1],0,0,0); \
        acc[2][0] = __builtin_amdgcn_mfma_f32_16x16x32_bf16(u2s8(Ac), sb0, acc[2][0],0,0,0); \
        acc[2][1] = __builtin_amdgcn_mfma_f32_16x16x32_bf16(u2s8(Ac), sb1, acc[2][1],0,0,0); \
        acc[3][0] = __builtin_amdgcn_mfma_f32_16x16x32_bf16(u2s8(Ad), sb0, acc[3][0],0,0,0); \
        acc[3][1] = __builtin_amdgcn_mfma_f32_16x16x32_bf16(u2s8(Ad), sb1, acc[3][1],0,0,0); \
    }

    auto consumeQ = [&](int q){
        uint4 A0,A1,A2,A3,B0,B1, C0,C1,C2,C3,D0,D1;
        const int base = q*8;
        LDCH(A0,A1,A2,A3,B0,B1, base+0)
        #pragma unroll
        for(int i=0;i<8;i+=2){
            LDCH(C0,C1,C2,C3,D0,D1, base+i+1)
            STEP(A0,A1,A2,A3,B0,B1)
            if(i<6){ LDCH(A0,A1,A2,A3,B0,B1, base+i+2) }
            STEP(C0,C1,C2,C3,D0,D1)
        }
    };

    __syncthreads();                       // lds_e2 visible

    loadAdjQ(0);
    produceQ(0);                            // Q0 exposed (unavoidable head)
    loadAdjQ(1);                            // Q1 adj in flight across barrier
    asm volatile("s_waitcnt lgkmcnt(0)\n\ts_barrier" ::: "memory");   // Q0 P visible

    // seg 0: produce Q1 | load adj Q2 | consume Q0
    produceQ(1);
    loadAdjQ(2);
    consumeQ(0);
    asm volatile("s_waitcnt lgkmcnt(0)\n\ts_barrier" ::: "memory");   // Q1 P visible

    // seg 1: produce Q2 | load adj Q3 | consume Q1
    produceQ(2);
    loadAdjQ(3);
    consumeQ(1);
    asm volatile("s_waitcnt lgkmcnt(0)\n\ts_barrier" ::: "memory");   // Q2 P visible

    // seg 2: produce Q3 | dsums finalize | consume Q2
    produceQ(3);
    dsum += __shfl_xor(dsum, 1, 64);
    dsum += __shfl_xor(dsum, 2, 64);
    dsum += __shfl_xor(dsum, 4, 64);
    dsum += __shfl_xor(dsum, 8, 64);
    if(qL == 0) dsums[wv*4 + rowL] = dsum;
    consumeQ(2);
    asm volatile("s_waitcnt lgkmcnt(0)\n\ts_barrier" ::: "memory");   // Q3 P + dsums visible

    // seg 3: consume Q3
    consumeQ(3);

    // ---- epilogue: scale, ELU, fp32 store ----
    float invv[4][4];
    #pragma unroll
    for(int ns=0;ns<4;ns++)
        #pragma unroll
        for(int r=0;r<4;r++)
            invv[ns][r] = 1.0f / fmaxf(dsums[ns*16 + quad*4 + r], 1e-30f);

    #pragma unroll
    for(int ns=0;ns<4;ns++){
        #pragma unroll
        for(int ct=0;ct<2;ct++){
            #pragma unroll
            for(int r=0;r<4;r++){
                float v = acc[ns][ct][r] * invv[ns][r];
                v = (v > 0.f) ? v : (__expf(v) - 1.f);
                int n_out = n0 + ns*16 + quad*4 + r;
                out[((size_t)(b*N_ + n_out))*F_ + fqq*32 + ct*16 + r16] = v;
            }
        }
    }
    #undef LDCH
    #undef STEP
}

extern "C" void kernel_launch(void* const* d_in, const int* in_sizes, int n_in,
                              void* d_out, int out_size, void* d_ws, size_t ws_size,
                              hipStream_t stream) {
    const float* X  = (const float*)d_in[0];   // [16,1024,512] fp32
    const int* adj  = (const int*)d_in[1];     // [16,1024,1024] int32
    const float* W  = (const float*)d_in[2];   // [512,512] fp32
    const float* a1 = (const float*)d_in[3];   // [512]
    const float* a2 = (const float*)d_in[4];   // [512]
    float* out = (float*)d_out;                // [16,1024,512] fp32

    float* ws    = (float*)d_ws;
    float* d1acc = ws + 1024;                  // fully written by k_prep (no memset needed)
    float* d2acc = ws + 1024 + 16384;
    u16*  XT     = (u16*)(ws + 50176);         // 16.78 MB bf16 [b][f][m]

    hipMemsetAsync(ws, 0, 1024*sizeof(float), stream);    // zero w1/w2 only
    k_w12<<<64, 256, 0, stream>>>(W, a1, a2, ws);
    k_prep<<<dim3(16, 16), 1024, 0, stream>>>(X, ws, XT, d1acc, d2acc);
    k_main<<<dim3(16, 16), 1024, 0, stream>>>(XT, adj, d1acc, d2acc, out);
}

// Round 15
// 179.968 us; speedup vs baseline: 1.0104x; 1.0104x over previous
//
#include <hip/hip_runtime.h>
#include <stdint.h>

typedef unsigned int u32;
typedef unsigned short u16;

#define N_  1024
#define F_  512
#define ALPHA 0.2f
#define TSTR2 72   // k_prep LDS tile stride (u16): 144 B rows -> 16B-aligned b128 reads, 2-way (free)

typedef __attribute__((ext_vector_type(8))) short short8;
typedef __attribute__((ext_vector_type(4))) float float4v;

union Frag { short8 s; u32 u[4]; };

static __device__ __forceinline__ float bits2f(u32 b){ union{u32 u; float f;} c; c.u=b; return c.f; }
static __device__ __forceinline__ u32   f2bits(float f){ union{float f_; u32 u;} c; c.f_=f; return c.u; }
static __device__ __forceinline__ float bflo(u32 p){ return bits2f(p<<16); }
static __device__ __forceinline__ float bfhi(u32 p){ return bits2f(p & 0xffff0000u); }
static __device__ __forceinline__ u32   f2bf(float f){ u32 u=f2bits(f); return (u + 0x7fffu + ((u>>16)&1u))>>16; }
static __device__ __forceinline__ u32   cvt_pk_bf16(float lo, float hi){
    u32 r; asm("v_cvt_pk_bf16_f32 %0, %1, %2" : "=v"(r) : "v"(lo), "v"(hi)); return r;
}
static __device__ __forceinline__ short8 u2s8(uint4 u){ Frag f; f.u[0]=u.x; f.u[1]=u.y; f.u[2]=u.z; f.u[3]=u.w; return f.s; }

// ---- kernel 1: w1 = W^T a1, w2 = W^T a2 (atomic partial sums into ws[0..1024)) ----
__global__ void k_w12(const float* __restrict__ W, const float* __restrict__ a1,
                      const float* __restrict__ a2, float* __restrict__ ws){
    int t = threadIdx.x;          // 256 threads: f = t and t+256
    int bo = blockIdx.x;          // 64 blocks: o-chunk of 8
    float s1a=0.f,s2a=0.f,s1b=0.f,s2b=0.f;
    #pragma unroll
    for(int i=0;i<8;i++){
        int o = bo*8+i;
        float av1 = a1[o], av2 = a2[o];
        float wa = W[o*F_ + t], wb = W[o*F_ + t + 256];
        s1a += wa*av1; s2a += wa*av2; s1b += wb*av1; s2b += wb*av2;
    }
    atomicAdd(&ws[t],       s1a); atomicAdd(&ws[512+t],     s2a);
    atomicAdd(&ws[t+256],   s1b); atomicAdd(&ws[512+t+256], s2b);
}

// ---- kernel 2: transpose X->XT bf16 + d1/d2 dots (R9 known-good, no atomics) ----
__global__ __launch_bounds__(1024)
void k_prep(const float* __restrict__ X, const float* __restrict__ ws,
            u16* __restrict__ XT, float* __restrict__ d1acc, float* __restrict__ d2acc){
    __shared__ u16 tile[4][64][TSTR2];   // 36 KB: [slice-group][f 64][m 64 +pad]
    __shared__ float dpart[2][4][64];    // 2 KB group-partial row dots

    const int t   = threadIdx.x;
    const int id  = blockIdx.x + (blockIdx.y << 4);   // 0..255
    const int xcd = id & 7, slot = id >> 3;
    const int b   = (xcd << 1) | (slot >> 4);
    const int m0  = (slot & 15) << 6;

    const int g    = t >> 8;             // slice group 0..3
    const int tid2 = t & 255;
    const int mg   = tid2 >> 4;          // 0..15
    const int m4   = mg * 4;
    const int fq   = (tid2 & 15) * 4;

    float4 v[2][4];
    #pragma unroll
    for(int p=0;p<2;p++){
        const float* Xb = X + ((size_t)(b*N_ + m0 + m4))*F_ + (p*4+g)*64 + fq;
        #pragma unroll
        for(int i=0;i<4;i++) v[p][i] = *(const float4*)(Xb + (size_t)i*F_);
    }

    float d1p[4]={0.f,0.f,0.f,0.f}, d2p[4]={0.f,0.f,0.f,0.f};
    #pragma unroll
    for(int p=0;p<2;p++){
        float4 w1q = *(const float4*)(ws + (p*4+g)*64 + fq);
        float4 w2q = *(const float4*)(ws + 512 + (p*4+g)*64 + fq);
        #pragma unroll
        for(int i=0;i<4;i++){
            d1p[i] += v[p][i].x*w1q.x + v[p][i].y*w1q.y + v[p][i].z*w1q.z + v[p][i].w*w1q.w;
            d2p[i] += v[p][i].x*w2q.x + v[p][i].y*w2q.y + v[p][i].z*w2q.z + v[p][i].w*w2q.w;
        }
    }

    #define TPOSE(P) { \
        u32 l0 = cvt_pk_bf16(v[P][0].x, v[P][1].x), h0 = cvt_pk_bf16(v[P][2].x, v[P][3].x); \
        *(uint2*)&tile[g][fq+0][m4] = (uint2){l0,h0}; \
        u32 l1 = cvt_pk_bf16(v[P][0].y, v[P][1].y), h1 = cvt_pk_bf16(v[P][2].y, v[P][3].y); \
        *(uint2*)&tile[g][fq+1][m4] = (uint2){l1,h1}; \
        u32 l2 = cvt_pk_bf16(v[P][0].z, v[P][1].z), h2 = cvt_pk_bf16(v[P][2].z, v[P][3].z); \
        *(uint2*)&tile[g][fq+2][m4] = (uint2){l2,h2}; \
        u32 l3 = cvt_pk_bf16(v[P][0].w, v[P][1].w), h3 = cvt_pk_bf16(v[P][2].w, v[P][3].w); \
        *(uint2*)&tile[g][fq+3][m4] = (uint2){l3,h3}; \
    }
    const int f_loc = tid2 >> 2;
    const int mo    = (tid2 & 3) * 16;
    #define XTOUT(P) { \
        uint4 q0 = *(const uint4*)&tile[g][f_loc][mo]; \
        uint4 q1 = *(const uint4*)&tile[g][f_loc][mo+8]; \
        u16* dst = XT + ((size_t)(b*F_ + (P*4+g)*64 + f_loc))*N_ + m0 + mo; \
        *(uint4*)dst = q0; *(uint4*)(dst+8) = q1; \
    }

    TPOSE(0)
    __syncthreads();
    XTOUT(0)
    __syncthreads();
    TPOSE(1)
    #pragma unroll
    for(int s2=1;s2<16;s2<<=1){
        #pragma unroll
        for(int i=0;i<4;i++){ d1p[i] += __shfl_xor(d1p[i],s2,64); d2p[i] += __shfl_xor(d2p[i],s2,64); }
    }
    if((t & 15) == 0){
        #pragma unroll
        for(int i=0;i<4;i++){ dpart[0][g][m4+i] = d1p[i]; dpart[1][g][m4+i] = d2p[i]; }
    }
    __syncthreads();
    XTOUT(1)
    if(t < 64){
        float s1 = dpart[0][0][t] + dpart[0][1][t] + dpart[0][2][t] + dpart[0][3][t];
        float s2 = dpart[1][0][t] + dpart[1][1][t] + dpart[1][2][t] + dpart[1][3][t];
        d1acc[b*N_ + m0 + t] = s1;
        d2acc[b*N_ + m0 + t] = s2;
    }
}

// ---- kernel 3: quartered producer/consumer pipeline over materialized P ----
// grid (16,16) = 256 blocks = 1/CU, 1024 threads = 16 waves. LDS 132 KB.
// IDENTICAL to round-14 except __launch_bounds__(1024, 4): min 4 waves/EU -> VGPR cap
// 128 (vs the allocator's 64-VGPR/8-wave heuristic choice, which is useless here since
// 132 KB LDS caps occupancy at 1 block/CU = 4 waves/SIMD anyway). R14 evidence: VGPR=64
// + WRITE_SIZE +7.2 MB scratch = the software pipeline was spilled/serialized. This cap
// lets the 12-uint4 prefetch set + acc[4][2] live in registers.
__global__ __launch_bounds__(1024, 4)
void k_main(const u16* __restrict__ XT, const int* __restrict__ adj,
            const float* __restrict__ d1acc, const float* __restrict__ d2acc,
            float* __restrict__ out){
    __shared__ u16 pbuf[32][4][512];   // 128 KB: P A-frags [chunk][nsub][lane*8]
    __shared__ u32 lds_e2[N_];         // 4 KB exp(f2)/exp(.2 f2) bf16-pair table
    __shared__ float dsums[64];        // row softmax denominators

    const int t    = threadIdx.x;
    const int lane = t & 63;
    const int wv   = t >> 6;           // 0..15
    const int fqq  = wv;               // consumer: f-slice of 32 (0..15)
    const int id   = blockIdx.x + (blockIdx.y << 4);
    const int xcd  = id & 7, slot = id >> 3;
    const int b    = (xcd << 1) | (slot >> 4);
    const int n0   = (slot & 15) << 6;
    const int r16  = lane & 15;
    const int quad = lane >> 4;
    const int rowL = lane >> 4;        // producer: row 0..3 within wave's quartet
    const int qL   = lane & 15;        // producer: col-pair index

    {
        float dv = d2acc[(size_t)b*N_ + t];
        lds_e2[t] = f2bf(__expf(dv)) | (f2bf(__expf(ALPHA*dv))<<16);
    }
    const float d1v  = d1acc[b*N_ + n0 + wv*4 + rowL];
    const float e1pL = __expf(d1v);
    const float e1nL = __expf(ALPHA*d1v);
    const int* adjLane = adj + ((size_t)(b*N_ + n0 + wv*4 + rowL))*N_ + qL*2;
    const u16* XTb = XT + (size_t)b*F_*N_;

    float dsum = 0.f;
    const int pOff = ((wv&3)*4 + rowL + (qL>>2)*16)*8 + (qL&3)*2;

    int2 adjR[8];                      // adj regs for one quarter (8 chunks)
    auto loadAdjQ = [&](int q){
        #pragma unroll
        for(int k=0;k<8;k++) adjR[k] = *(const int2*)(adjLane + (q*8+k)*32);
    };
    auto produceQ = [&](int q){
        #pragma unroll
        for(int k=0;k<8;k++){
            int c = q*8 + k;
            uint2 ev = *(const uint2*)(&lds_e2[c*32 + qL*2]);
            float p0 = fmaxf(e1pL*bflo(ev.x), e1nL*bfhi(ev.x)); p0 = adjR[k].x ? p0 : 0.f;
            float p1 = fmaxf(e1pL*bflo(ev.y), e1nL*bfhi(ev.y)); p1 = adjR[k].y ? p1 : 0.f;
            dsum += p0 + p1;
            *(u32*)(&pbuf[c][wv>>2][pOff]) = cvt_pk_bf16(p0, p1);
        }
    };

    // consumer state
    float4v acc[4][2];
    #pragma unroll
    for(int ns=0;ns<4;ns++){ acc[ns][0]=(float4v){0,0,0,0}; acc[ns][1]=(float4v){0,0,0,0}; }
    const u16* pA  = &pbuf[0][0][0];
    const u16* bB0 = XTb + (size_t)(fqq*32 +      r16)*N_ + quad*8;   // ct=0 rows
    const u16* bB1 = XTb + (size_t)(fqq*32 + 16 + r16)*N_ + quad*8;   // ct=1 rows

    #define LDCH(Aa,Ab,Ac,Ad,Bx,By,I) \
        Aa = *(const uint4*)(pA + ((I)*4+0)*512 + lane*8); \
        Ab = *(const uint4*)(pA + ((I)*4+1)*512 + lane*8); \
        Ac = *(const uint4*)(pA + ((I)*4+2)*512 + lane*8); \
        Ad = *(const uint4*)(pA + ((I)*4+3)*512 + lane*8); \
        Bx = *(const uint4*)(bB0 + (I)*32); \
        By = *(const uint4*)(bB1 + (I)*32);

    #define STEP(Aa,Ab,Ac,Ad,Bx,By) { \
        short8 sb0 = u2s8(Bx), sb1 = u2s8(By); \
        acc[0][0] = __builtin_amdgcn_mfma_f32_16x16x32_bf16(u2s8(Aa), sb0, acc[0][0],0,0,0); \
        acc[0][1] = __builtin_amdgcn_mfma_f32_16x16x32_bf16(u2s8(Aa), sb1, acc[0][1],0,0,0); \
        acc[1][0] = __builtin_amdgcn_mfma_f32_16x16x32_bf16(u2s8(Ab), sb0, acc[1][0],0,0,0); \
        acc[1][1] = __builtin_amdgcn_mfma_f32_16x16x32_bf16(u2s8(Ab), sb1, acc[1][1],0,0,0); \
        acc[2][0] = __builtin_amdgcn_mfma_f32_16x16x32_bf16(u2s8(Ac), sb0, acc[2][0],0,0,0); \
        acc[2][1] = __builtin_amdgcn_mfma_f32_16x16x32_bf16(u2s8(Ac), sb1, acc[2][1],0,0,0); \
        acc[3][0] = __builtin_amdgcn_mfma_f32_16x16x32_bf16(u2s8(Ad), sb0, acc[3][0],0,0,0); \
        acc[3][1] = __builtin_amdgcn_mfma_f32_16x16x32_bf16(u2s8(Ad), sb1, acc[3][1],0,0,0); \
    }

    auto consumeQ = [&](int q){
        uint4 A0,A1,A2,A3,B0,B1, C0,C1,C2,C3,D0,D1;
        const int base = q*8;
        LDCH(A0,A1,A2,A3,B0,B1, base+0)
        #pragma unroll
        for(int i=0;i<8;i+=2){
            LDCH(C0,C1,C2,C3,D0,D1, base+i+1)
            STEP(A0,A1,A2,A3,B0,B1)
            if(i<6){ LDCH(A0,A1,A2,A3,B0,B1, base+i+2) }
            STEP(C0,C1,C2,C3,D0,D1)
        }
    };

    __syncthreads();                       // lds_e2 visible

    loadAdjQ(0);
    produceQ(0);                            // Q0 exposed (unavoidable head)
    loadAdjQ(1);                            // Q1 adj in flight across barrier
    asm volatile("s_waitcnt lgkmcnt(0)\n\ts_barrier" ::: "memory");   // Q0 P visible

    // seg 0: produce Q1 | load adj Q2 | consume Q0
    produceQ(1);
    loadAdjQ(2);
    consumeQ(0);
    asm volatile("s_waitcnt lgkmcnt(0)\n\ts_barrier" ::: "memory");   // Q1 P visible

    // seg 1: produce Q2 | load adj Q3 | consume Q1
    produceQ(2);
    loadAdjQ(3);
    consumeQ(1);
    asm volatile("s_waitcnt lgkmcnt(0)\n\ts_barrier" ::: "memory");   // Q2 P visible

    // seg 2: produce Q3 | dsums finalize | consume Q2
    produceQ(3);
    dsum += __shfl_xor(dsum, 1, 64);
    dsum += __shfl_xor(dsum, 2, 64);
    dsum += __shfl_xor(dsum, 4, 64);
    dsum += __shfl_xor(dsum, 8, 64);
    if(qL == 0) dsums[wv*4 + rowL] = dsum;
    consumeQ(2);
    asm volatile("s_waitcnt lgkmcnt(0)\n\ts_barrier" ::: "memory");   // Q3 P + dsums visible

    // seg 3: consume Q3
    consumeQ(3);

    // ---- epilogue: scale, ELU, fp32 store ----
    float invv[4][4];
    #pragma unroll
    for(int ns=0;ns<4;ns++)
        #pragma unroll
        for(int r=0;r<4;r++)
            invv[ns][r] = 1.0f / fmaxf(dsums[ns*16 + quad*4 + r], 1e-30f);

    #pragma unroll
    for(int ns=0;ns<4;ns++){
        #pragma unroll
        for(int ct=0;ct<2;ct++){
            #pragma unroll
            for(int r=0;r<4;r++){
                float v = acc[ns][ct][r] * invv[ns][r];
                v = (v > 0.f) ? v : (__expf(v) - 1.f);
                int n_out = n0 + ns*16 + quad*4 + r;
                out[((size_t)(b*N_ + n_out))*F_ + fqq*32 + ct*16 + r16] = v;
            }
        }
    }
    #undef LDCH
    #undef STEP
}

extern "C" void kernel_launch(void* const* d_in, const int* in_sizes, int n_in,
                              void* d_out, int out_size, void* d_ws, size_t ws_size,
                              hipStream_t stream) {
    const float* X  = (const float*)d_in[0];   // [16,1024,512] fp32
    const int* adj  = (const int*)d_in[1];     // [16,1024,1024] int32
    const float* W  = (const float*)d_in[2];   // [512,512] fp32
    const float* a1 = (const float*)d_in[3];   // [512]
    const float* a2 = (const float*)d_in[4];   // [512]
    float* out = (float*)d_out;                // [16,1024,512] fp32

    float* ws    = (float*)d_ws;
    float* d1acc = ws + 1024;                  // fully written by k_prep (no memset needed)
    float* d2acc = ws + 1024 + 16384;
    u16*  XT     = (u16*)(ws + 50176);         // 16.78 MB bf16 [b][f][m]

    hipMemsetAsync(ws, 0, 1024*sizeof(float), stream);    // zero w1/w2 only
    k_w12<<<64, 256, 0, stream>>>(W, a1, a2, ws);
    k_prep<<<dim3(16, 16), 1024, 0, stream>>>(X, ws, XT, d1acc, d2acc);
    k_main<<<dim3(16, 16), 1024, 0, stream>>>(XT, adj, d1acc, d2acc, out);
}